// Round 8
// baseline (449.746 us; speedup 1.0000x reference)
//
#include <hip/hip_runtime.h>
#include <math.h>

static constexpr int BB  = 4;
static constexpr int S   = 2048;
static constexpr int D   = 512;
static constexpr int DFF = 2048;
static constexpr int BS  = BB * S;   // 8192 rows

using v8h = __attribute__((ext_vector_type(8))) _Float16;
using v4f = __attribute__((ext_vector_type(4))) float;

// async global->LDS, 16 B per lane; LDS dest = wave-uniform base + lane*16
__device__ __forceinline__ void async16(const void* g, void* l) {
  __builtin_amdgcn_global_load_lds(
      (const __attribute__((address_space(1))) unsigned int*)g,
      (__attribute__((address_space(3))) unsigned int*)l, 16, 0, 0);
}

// ---- block-wide reductions (block = 256 threads = 4 waves) ----
__device__ __forceinline__ float blockSum(float v) {
#pragma unroll
  for (int o = 32; o; o >>= 1) v += __shfl_xor(v, o, 64);
  __shared__ float t[4];
  __syncthreads();
  if ((threadIdx.x & 63) == 0) t[threadIdx.x >> 6] = v;
  __syncthreads();
  return t[0] + t[1] + t[2] + t[3];
}
__device__ __forceinline__ float blockMax(float v) {
#pragma unroll
  for (int o = 32; o; o >>= 1) v = fmaxf(v, __shfl_xor(v, o, 64));
  __shared__ float t[4];
  __syncthreads();
  if ((threadIdx.x & 63) == 0) t[threadIdx.x >> 6] = v;
  __syncthreads();
  return fmaxf(fmaxf(t[0], t[1]), fmaxf(t[2], t[3]));
}

// ---- embedding gather + positional encoding; fp32 + fp16 copy ----
__global__ __launch_bounds__(256) void embed_pos_k(
    const int* __restrict__ seq, const float* __restrict__ emb,
    float* __restrict__ X, _Float16* __restrict__ Xh) {
  const int bs = blockIdx.x;
  const int s  = bs & (S - 1);
  const int idx = seq[bs];
  const float* er = emb + (size_t)idx * D;
#pragma unroll
  for (int t = 0; t < 2; ++t) {
    const int d = threadIdx.x + 256 * t;
    const double ang = (double)s / pow(10000.0, (2.0 * d) / (double)D);
    const float p = (d & 1) ? (float)cos(ang) : (float)sin(ang);
    const float val = (er[d] + p) * 22.62741699796952f;  // * sqrt(512)
    const size_t o = (size_t)bs * D + d;
    X[o] = val;
    Xh[o] = (_Float16)val;
  }
}

// ---- one-shot weight prep: transposed fp16 copies + concatenated qkv ----
// wcat[1536][512] = [wk^T; wq^T; wv^T]; w1T[2048][512]; w2T[512][2048];
// bcat[1536] = [bk; bq; bv]
__global__ __launch_bounds__(256) void prep_k(
    const float* __restrict__ wk, const float* __restrict__ wq,
    const float* __restrict__ wv, const float* __restrict__ w1,
    const float* __restrict__ w2, const float* __restrict__ bk,
    const float* __restrict__ bq, const float* __restrict__ bv,
    _Float16* __restrict__ wcat, _Float16* __restrict__ w1T,
    _Float16* __restrict__ w2T, float* __restrict__ bcat) {
  const int idx = blockIdx.x * 256 + threadIdx.x;
  if (idx < 786432) {                 // 3 x 512x512
    const int which = idx >> 18, e = idx & 262143;
    const int k = e >> 9, n = e & 511;
    const float* w = (which == 0) ? wk : (which == 1) ? wq : wv;
    wcat[((long)(which * 512 + n)) * 512 + k] = (_Float16)w[e];
  } else if (idx < 786432 + 1048576) {  // w1 [512][2048]
    const int e = idx - 786432;
    const int k = e >> 11, n = e & 2047;
    w1T[(long)n * 512 + k] = (_Float16)w1[e];
  } else if (idx < 786432 + 2097152) {  // w2 [2048][512]
    const int e = idx - 786432 - 1048576;
    const int k = e >> 9, n = e & 511;
    w2T[(long)n * 2048 + k] = (_Float16)w2[e];
  } else if (idx < 786432 + 2097152 + 1536) {
    const int e = idx - 786432 - 2097152;
    const float* b = (e < 512) ? bk : (e < 1024) ? bq : bv;
    bcat[e] = b[e & 511];
  }
}

// ---- MFMA GEMM: C = act(scale * A @ B^T + bias), fp16 in, fp32 acc ----
// A[M,K], B[N,K] row-major fp16. Tile TMx128, BK=64.
// OMODE: 0 = fp32, 1 = fp16, 4 = fused-QKV split: region = n0>>9
//        (0 -> kF[gm*512+gnl], 1 -> qF, 2 -> vT[z][gnl][gm&2047], z = gm>>11)
// Staging: global_load_lds w16; XOR swizzle chunk^=(row&7) (conflict-free).
template <int TM, int OMODE, int ACT>
__global__ __launch_bounds__(256) void mm_k(
    const _Float16* __restrict__ Ap, const _Float16* __restrict__ Bp,
    void* __restrict__ Cp, void* __restrict__ Cp2, void* __restrict__ Cp3,
    const float* __restrict__ bias,
    int N, int K, long sA, long sB, long sC, float scale) {
  constexpr int ATE = TM * 64;
  constexpr int BTE = 128 * 64;
  __shared__ __align__(16) _Float16 lds[ATE + BTE];
  _Float16* const Ah = lds;
  _Float16* const Bh = lds + ATE;

  const int tid = threadIdx.x, lane = tid & 63, w = tid >> 6;
  const int quad = lane >> 4, l16 = lane & 15;
  constexpr int MT = 4;
  constexpr int NT = (TM == 128) ? 4 : 2;
  constexpr int WN = (TM == 128) ? 64 : 32;
  const int wm = (TM == 128) ? (w >> 1) : 0;
  const int wn = (TM == 128) ? (w & 1) : w;
  const int m0 = blockIdx.y * TM, n0 = blockIdx.x * 128;

  const _Float16* A = Ap + (long)blockIdx.z * sA;
  const _Float16* B = Bp + (long)blockIdx.z * sB;

  v4f acc[MT][NT] = {};
  const int srow8 = lane >> 3;
  const int cs = (lane & 7) ^ srow8;
  const int lsw = l16 & 7;

  for (int k0 = 0; k0 < K; k0 += 64) {
    __syncthreads();
#pragma unroll
    for (int i = 0; i < TM / 32; ++i) {
      const int is = w + i * 4;
      async16(A + (long)(m0 + is * 8 + srow8) * K + k0 + cs * 8, Ah + is * 512);
    }
#pragma unroll
    for (int i = 0; i < 4; ++i) {
      const int is = w + i * 4;
      async16(B + (long)(n0 + is * 8 + srow8) * K + k0 + cs * 8, Bh + is * 512);
    }
    __syncthreads();

    v8h af[MT][2], bfr[NT][2];
#pragma unroll
    for (int mt = 0; mt < MT; ++mt) {
      const int rr = wm * 64 + mt * 16 + l16;
#pragma unroll
      for (int kk = 0; kk < 2; ++kk) {
        const int c = (kk * 4 + quad) ^ lsw;
        af[mt][kk] = *(v8h*)&Ah[rr * 64 + c * 8];
      }
    }
#pragma unroll
    for (int nt = 0; nt < NT; ++nt) {
      const int rn = wn * WN + nt * 16 + l16;
#pragma unroll
      for (int kk = 0; kk < 2; ++kk) {
        const int c = (kk * 4 + quad) ^ lsw;
        bfr[nt][kk] = *(v8h*)&Bh[rn * 64 + c * 8];
      }
    }
#pragma unroll
    for (int kk = 0; kk < 2; ++kk)
#pragma unroll
      for (int mt = 0; mt < MT; ++mt)
#pragma unroll
        for (int nt = 0; nt < NT; ++nt)
          acc[mt][nt] = __builtin_amdgcn_mfma_f32_16x16x32_f16(
              af[mt][kk], bfr[nt][kk], acc[mt][nt], 0, 0, 0);
  }

  // ---- epilogue (C layout: col = lane&15, row = quad*4 + reg) ----
  const long Cz = (long)blockIdx.z * sC;
  const int region = n0 >> 9;          // block-uniform (OMODE 4)
#pragma unroll
  for (int nt = 0; nt < NT; ++nt) {
    const int gn = n0 + wn * WN + nt * 16 + l16;
    const int gnl = gn & 511;
    const float bv = bias ? bias[gn] : 0.0f;
#pragma unroll
    for (int mt = 0; mt < MT; ++mt) {
      const int gmb = m0 + wm * 64 + mt * 16 + quad * 4;
#pragma unroll
      for (int r = 0; r < 4; ++r) {
        const int gm = gmb + r;
        float v = acc[mt][nt][r] * scale + bv;
        if constexpr (ACT == 1)
          v = 0.5f * v * (1.0f + erff(v * 0.7071067811865476f));
        if constexpr (OMODE == 0) {
          ((float*)Cp)[Cz + (long)gm * N + gn] = v;
        } else if constexpr (OMODE == 1) {
          ((_Float16*)Cp)[Cz + (long)gm * N + gn] = (_Float16)v;
        } else {  // OMODE 4: fused QKV
          if (region == 0) {
            ((_Float16*)Cp)[(long)gm * 512 + gnl] = (_Float16)v;
          } else if (region == 1) {
            ((_Float16*)Cp2)[(long)gm * 512 + gnl] = (_Float16)v;
          } else {
            const int z2 = gm >> 11, ml = gm & 2047;
            ((_Float16*)Cp3)[((long)z2 * 512 + gnl) * 2048 + ml] = (_Float16)v;
          }
        }
      }
    }
  }
}

// ---- per-row softmax stats over S=2048 fp16 logits: m and 1/sum ----
__global__ __launch_bounds__(256) void rowstat_k(
    const _Float16* __restrict__ Sc, float* __restrict__ mrow,
    float* __restrict__ linv) {
  const _Float16* p = Sc + (size_t)blockIdx.x * S;
  const int base = threadIdx.x * 8;
  const v8h a = *(const v8h*)(p + base);
  float v[8];
#pragma unroll
  for (int i = 0; i < 8; ++i) v[i] = (float)a[i];
  float m = -1e30f;
#pragma unroll
  for (int i = 0; i < 8; ++i) m = fmaxf(m, v[i]);
  m = blockMax(m);
  float sum = 0.f;
#pragma unroll
  for (int i = 0; i < 8; ++i) sum += exp2f((v[i] - m) * 1.44269504f);
  sum = blockSum(sum);
  if (threadIdx.x == 0) {
    mrow[blockIdx.x] = m;
    linv[blockIdx.x] = 1.0f / sum;
  }
}

// ---- fused softmax+PV: attn[z][m][n] = softmax(Sc[z][m])@V, B = vT[z][n][k] ----
// TM=64, N-tile 128, BK=64. A-staging: read Sc fp16, exp2(s-m[row]) in VALU,
// swizzled ds_write; epilogue scales by linv[row].
__global__ __launch_bounds__(256) void pv_k(
    const _Float16* __restrict__ Sc, const _Float16* __restrict__ vT,
    float* __restrict__ attn, const float* __restrict__ mrow,
    const float* __restrict__ linv) {
  constexpr int ATE = 64 * 64;
  constexpr int BTE = 128 * 64;
  __shared__ __align__(16) _Float16 lds[ATE + BTE];
  _Float16* const Ah = lds;
  _Float16* const Bh = lds + ATE;

  const int tid = threadIdx.x, lane = tid & 63, w = tid >> 6;
  const int quad = lane >> 4, l16 = lane & 15;
  const int z = blockIdx.z;
  const int m0 = blockIdx.y * 64, n0 = blockIdx.x * 128;

  const _Float16* Scz = Sc + (long)z * S * S;
  const _Float16* B = vT + (long)z * D * S;

  v4f acc[4][2] = {};
  const int srow8 = lane >> 3;
  const int cs = (lane & 7) ^ srow8;
  const int lsw = l16 & 7;

  // A-staging thread mapping: row = tid>>2 (fixed), chunks 2*(tid&3)+{0,1}
  const int ar = tid >> 2, ac2 = (tid & 3) * 2;
  const float mr = mrow[z * S + m0 + ar];

  for (int k0 = 0; k0 < S; k0 += 64) {
    __syncthreads();
    // A tile: exp-transformed Sc rows
#pragma unroll
    for (int j = 0; j < 2; ++j) {
      const int g = ac2 + j;
      const v8h s8 = *(const v8h*)(Scz + (long)(m0 + ar) * S + k0 + g * 8);
      v8h e8;
#pragma unroll
      for (int i = 0; i < 8; ++i)
        e8[i] = (_Float16)exp2f(((float)s8[i] - mr) * 1.44269504f);
      *(v8h*)&Ah[ar * 64 + (g ^ (ar & 7)) * 8] = e8;
    }
    // B tile: vT rows n0..n0+127, via async copy
#pragma unroll
    for (int i = 0; i < 4; ++i) {
      const int is = w + i * 4;
      async16(B + (long)(n0 + is * 8 + srow8) * S + k0 + cs * 8, Bh + is * 512);
    }
    __syncthreads();

    v8h af[4][2], bfr[2][2];
#pragma unroll
    for (int mt = 0; mt < 4; ++mt) {
      const int rr = mt * 16 + l16;
#pragma unroll
      for (int kk = 0; kk < 2; ++kk)
        af[mt][kk] = *(v8h*)&Ah[rr * 64 + (((kk * 4 + quad) ^ lsw)) * 8];
    }
#pragma unroll
    for (int nt = 0; nt < 2; ++nt) {
      const int rn = w * 32 + nt * 16 + l16;
#pragma unroll
      for (int kk = 0; kk < 2; ++kk)
        bfr[nt][kk] = *(v8h*)&Bh[rn * 64 + (((kk * 4 + quad) ^ lsw)) * 8];
    }
#pragma unroll
    for (int kk = 0; kk < 2; ++kk)
#pragma unroll
      for (int mt = 0; mt < 4; ++mt)
#pragma unroll
        for (int nt = 0; nt < 2; ++nt)
          acc[mt][nt] = __builtin_amdgcn_mfma_f32_16x16x32_f16(
              af[mt][kk], bfr[nt][kk], acc[mt][nt], 0, 0, 0);
  }

#pragma unroll
  for (int nt = 0; nt < 2; ++nt) {
    const int gn = n0 + w * 32 + nt * 16 + l16;
#pragma unroll
    for (int mt = 0; mt < 4; ++mt) {
      const int gmb = m0 + mt * 16 + quad * 4;
#pragma unroll
      for (int r = 0; r < 4; ++r) {
        const int gm = gmb + r;
        attn[((long)z * S + gm) * D + gn] = acc[mt][nt][r] * linv[z * S + gm];
      }
    }
  }
}

// ---- r = LayerNorm(X + Add) -> X (in place) + fp16 copy rF ----
__global__ __launch_bounds__(256) void ln_res_k(
    float* __restrict__ X, const float* __restrict__ Add,
    const float* __restrict__ g, const float* __restrict__ b,
    _Float16* __restrict__ rF) {
  float* xr = X + (size_t)blockIdx.x * D;
  const float* ar = Add + (size_t)blockIdx.x * D;
  _Float16* rf = rF + (size_t)blockIdx.x * D;
  const int t0 = threadIdx.x, t1 = threadIdx.x + 256;
  const float z0 = xr[t0] + ar[t0];
  const float z1 = xr[t1] + ar[t1];
  const float mu = blockSum(z0 + z1) * (1.0f / D);
  const float d0 = z0 - mu, d1 = z1 - mu;
  const float var = blockSum(d0 * d0 + d1 * d1) * (1.0f / D);
  const float rs = rsqrtf(var + 1e-5f);
  const float v0 = d0 * rs * g[t0] + b[t0];
  const float v1 = d1 * rs * g[t1] + b[t1];
  xr[t0] = v0; xr[t1] = v1;
  rf[t0] = (_Float16)v0; rf[t1] = (_Float16)v1;
}

// ---- out = LayerNorm(R + F), fp32 ----
__global__ __launch_bounds__(256) void ln_out_k(
    const float* __restrict__ R, const float* __restrict__ F,
    const float* __restrict__ g, const float* __restrict__ b,
    float* __restrict__ out) {
  const float* rr = R + (size_t)blockIdx.x * D;
  const float* fr = F + (size_t)blockIdx.x * D;
  float* orow = out + (size_t)blockIdx.x * D;
  const int t0 = threadIdx.x, t1 = threadIdx.x + 256;
  const float z0 = rr[t0] + fr[t0];
  const float z1 = rr[t1] + fr[t1];
  const float mu = blockSum(z0 + z1) * (1.0f / D);
  const float d0 = z0 - mu, d1 = z1 - mu;
  const float var = blockSum(d0 * d0 + d1 * d1) * (1.0f / D);
  const float rs = rsqrtf(var + 1e-5f);
  orow[t0] = d0 * rs * g[t0] + b[t0];
  orow[t1] = d1 * rs * g[t1] + b[t1];
}

extern "C" void kernel_launch(void* const* d_in, const int* in_sizes, int n_in,
                              void* d_out, int out_size, void* d_ws, size_t ws_size,
                              hipStream_t stream) {
  (void)in_sizes; (void)n_in; (void)out_size; (void)ws_size;
  const int*   seq = (const int*)d_in[0];
  const float* emb = (const float*)d_in[1];
  const float* wk  = (const float*)d_in[2];
  const float* bk  = (const float*)d_in[3];
  const float* wq  = (const float*)d_in[4];
  const float* bq  = (const float*)d_in[5];
  const float* wv  = (const float*)d_in[6];
  const float* bv  = (const float*)d_in[7];
  const float* lng = (const float*)d_in[8];
  const float* lnb = (const float*)d_in[9];
  const float* w1  = (const float*)d_in[10];
  const float* b1  = (const float*)d_in[11];
  const float* w2  = (const float*)d_in[12];
  const float* b2  = (const float*)d_in[13];

  // Workspace (MB offsets, lifetimes):
  //  [0,16)    X fp32 (x -> r in-place)
  //  [16,24)   Xh fp16 (dead after QKV)
  //  [24,32)   kF fp16 (dead after scores)  -> rF fp16
  //  [32,40)   qF fp16 (dead after scores)  -> ff fp32 [32,48)
  //  [40,48)   vT fp16 [z][D][S]            (ff tail; vT dead after PV)
  //  [48,80)   Sc fp16 (dead after PV)      -> hF fp16
  //  [80,81)   mrow fp32 (32KB) | linv fp32 (32KB)
  //  [81,97)   attn fp32 (dead after ln_res)
  //  [100,...) wcat 1.5MB, bcat 8KB, w1T 2MB, w2T 2MB
  const size_t MBy = 1024 * 1024;
  char* wsb = (char*)d_ws;
  float*    X    = (float*)wsb;
  _Float16* Xh   = (_Float16*)(wsb + 16 * MBy);
  _Float16* kF   = (_Float16*)(wsb + 24 * MBy);
  _Float16* qF   = (_Float16*)(wsb + 32 * MBy);
  _Float16* vT   = (_Float16*)(wsb + 40 * MBy);
  _Float16* Sc   = (_Float16*)(wsb + 48 * MBy);
  float*    mrow = (float*)(wsb + 80 * MBy);
  float*    linv = (float*)(wsb + 80 * MBy + 512 * 1024);
  float*    attn = (float*)(wsb + 81 * MBy);
  _Float16* rF   = (_Float16*)(wsb + 24 * MBy);
  _Float16* hF   = (_Float16*)(wsb + 48 * MBy);
  float*    ff   = (float*)(wsb + 32 * MBy);
  _Float16* wcat = (_Float16*)(wsb + 100 * MBy);
  float*    bcat = (float*)(wsb + 102 * MBy);
  _Float16* w1T  = (_Float16*)(wsb + 103 * MBy);
  _Float16* w2T  = (_Float16*)(wsb + 105 * MBy);

  const long SD = (long)S * D, SSl = (long)S * S;

  prep_k<<<11270, 256, 0, stream>>>(wk, wq, wv, w1, w2, bk, bq, bv,
                                    wcat, w1T, w2T, bcat);
  embed_pos_k<<<BS, 256, 0, stream>>>(seq, emb, X, Xh);

  // fused QKV projection: [8192,512] @ wcat^T[512,1536], split epilogue
  mm_k<128, 4, 0><<<dim3(12, 64, 1), 256, 0, stream>>>(
      Xh, wcat, kF, qF, vT, bcat, 1536, D, 0, 0, 0, 1.0f);

  // scores = (k @ q^T)/sqrt(D) -> fp16, batched
  mm_k<128, 1, 0><<<dim3(16, 16, BB), 256, 0, stream>>>(
      kF, qF, Sc, nullptr, nullptr, nullptr, S, D, SD, SD, SSl,
      0.044194173824159216f);

  // softmax stats (m, 1/l per row)
  rowstat_k<<<BS, 256, 0, stream>>>(Sc, mrow, linv);

  // attn = softmax(Sc) @ v, fused exp in staging, batched
  pv_k<<<dim3(4, 32, BB), 256, 0, stream>>>(Sc, vT, attn, mrow, linv);

  // r = LN(x + attn) -> X (+ fp16 rF)
  ln_res_k<<<BS, 256, 0, stream>>>(X, attn, lng, lnb, rF);

  // h = gelu(r @ w1 + b1) -> fp16
  mm_k<128, 1, 1><<<dim3(16, 64, 1), 256, 0, stream>>>(
      rF, w1T, hF, nullptr, nullptr, b1, DFF, D, 0, 0, 0, 1.0f);
  // ff = h @ w2 + b2 -> fp32
  mm_k<64, 0, 0><<<dim3(4, 128, 1), 256, 0, stream>>>(
      hF, w2T, ff, nullptr, nullptr, b2, D, DFF, 0, 0, 0, 1.0f);

  // out = LN(r + ff)
  ln_out_k<<<BS, 256, 0, stream>>>(X, ff, lng, lnb, (float*)d_out);
}

// Round 9
// 389.937 us; speedup vs baseline: 1.1534x; 1.1534x over previous
//
#include <hip/hip_runtime.h>
#include <math.h>

static constexpr int BB  = 4;
static constexpr int S   = 2048;
static constexpr int D   = 512;
static constexpr int DFF = 2048;
static constexpr int BS  = BB * S;   // 8192 rows

using v8h = __attribute__((ext_vector_type(8))) _Float16;
using v4h = __attribute__((ext_vector_type(4))) _Float16;
using v4f = __attribute__((ext_vector_type(4))) float;

// async global->LDS, 16 B per lane; LDS dest = wave-uniform base + lane*16
__device__ __forceinline__ void async16(const void* g, void* l) {
  __builtin_amdgcn_global_load_lds(
      (const __attribute__((address_space(1))) unsigned int*)g,
      (__attribute__((address_space(3))) unsigned int*)l, 16, 0, 0);
}

// ---- block-wide reductions (block = 256 threads = 4 waves) ----
__device__ __forceinline__ float blockSum(float v) {
#pragma unroll
  for (int o = 32; o; o >>= 1) v += __shfl_xor(v, o, 64);
  __shared__ float t[4];
  __syncthreads();
  if ((threadIdx.x & 63) == 0) t[threadIdx.x >> 6] = v;
  __syncthreads();
  return t[0] + t[1] + t[2] + t[3];
}
__device__ __forceinline__ float blockMax(float v) {
#pragma unroll
  for (int o = 32; o; o >>= 1) v = fmaxf(v, __shfl_xor(v, o, 64));
  __shared__ float t[4];
  __syncthreads();
  if ((threadIdx.x & 63) == 0) t[threadIdx.x >> 6] = v;
  __syncthreads();
  return fmaxf(fmaxf(t[0], t[1]), fmaxf(t[2], t[3]));
}

// ---- embedding gather + positional encoding (fp32 math); fp32 + fp16 copy ----
__global__ __launch_bounds__(256) void embed_pos_k(
    const int* __restrict__ seq, const float* __restrict__ emb,
    float* __restrict__ X, _Float16* __restrict__ Xh) {
  const int bs = blockIdx.x;
  const int s  = bs & (S - 1);
  const int idx = seq[bs];
  const float* er = emb + (size_t)idx * D;
  // ang = s * 10000^(-2d/D) = s * exp2(d * -2*log2(1e4)/512)
  const float cexp = -0.05190512648261504f;
#pragma unroll
  for (int t = 0; t < 2; ++t) {
    const int d = threadIdx.x + 256 * t;
    const float ang = (float)s * exp2f((float)d * cexp);
    const float p = (d & 1) ? cosf(ang) : sinf(ang);
    const float val = (er[d] + p) * 22.62741699796952f;  // * sqrt(512)
    const size_t o = (size_t)bs * D + d;
    X[o] = val;
    Xh[o] = (_Float16)val;
  }
}

// ---- one-shot weight prep: transposed fp16 copies + concatenated qkv ----
// wcat[1536][512] = [wk^T; wq^T; wv^T]; w1T[2048][512]; w2T[512][2048];
// bcat[1536] = [bk; bq; bv]
__global__ __launch_bounds__(256) void prep_k(
    const float* __restrict__ wk, const float* __restrict__ wq,
    const float* __restrict__ wv, const float* __restrict__ w1,
    const float* __restrict__ w2, const float* __restrict__ bk,
    const float* __restrict__ bq, const float* __restrict__ bv,
    _Float16* __restrict__ wcat, _Float16* __restrict__ w1T,
    _Float16* __restrict__ w2T, float* __restrict__ bcat) {
  const int idx = blockIdx.x * 256 + threadIdx.x;
  if (idx < 786432) {                 // 3 x 512x512
    const int which = idx >> 18, e = idx & 262143;
    const int k = e >> 9, n = e & 511;
    const float* w = (which == 0) ? wk : (which == 1) ? wq : wv;
    wcat[((long)(which * 512 + n)) * 512 + k] = (_Float16)w[e];
  } else if (idx < 786432 + 1048576) {  // w1 [512][2048]
    const int e = idx - 786432;
    const int k = e >> 11, n = e & 2047;
    w1T[(long)n * 512 + k] = (_Float16)w1[e];
  } else if (idx < 786432 + 2097152) {  // w2 [2048][512]
    const int e = idx - 786432 - 1048576;
    const int k = e >> 9, n = e & 511;
    w2T[(long)n * 2048 + k] = (_Float16)w2[e];
  } else if (idx < 786432 + 2097152 + 1536) {
    const int e = idx - 786432 - 2097152;
    const float* b = (e < 512) ? bk : (e < 1024) ? bq : bv;
    bcat[e] = b[e & 511];
  }
}

// ---- MFMA GEMM: C = act(scale * A @ B^T + bias), fp16 in, fp32 acc ----
// A[M,K], B[N,K] row-major fp16. Tile TMx128, BK=64.
// OMODE: 0 = fp32, 1 = fp16, 4 = fused-QKV split: region = n0>>9
//        (0 -> kF[gm*512+gnl], 1 -> qF, 2 -> vT[z][gnl][gm&2047], z = gm>>11)
// Staging: global_load_lds w16; XOR swizzle chunk^=(row&7) (conflict-free).
template <int TM, int OMODE, int ACT>
__global__ __launch_bounds__(256) void mm_k(
    const _Float16* __restrict__ Ap, const _Float16* __restrict__ Bp,
    void* __restrict__ Cp, void* __restrict__ Cp2, void* __restrict__ Cp3,
    const float* __restrict__ bias,
    int N, int K, long sA, long sB, long sC, float scale) {
  constexpr int ATE = TM * 64;
  constexpr int BTE = 128 * 64;
  __shared__ __align__(16) _Float16 lds[ATE + BTE];
  _Float16* const Ah = lds;
  _Float16* const Bh = lds + ATE;

  const int tid = threadIdx.x, lane = tid & 63, w = tid >> 6;
  const int quad = lane >> 4, l16 = lane & 15;
  constexpr int MT = 4;
  constexpr int NT = (TM == 128) ? 4 : 2;
  constexpr int WN = (TM == 128) ? 64 : 32;
  const int wm = (TM == 128) ? (w >> 1) : 0;
  const int wn = (TM == 128) ? (w & 1) : w;
  const int m0 = blockIdx.y * TM, n0 = blockIdx.x * 128;

  const _Float16* A = Ap + (long)blockIdx.z * sA;
  const _Float16* B = Bp + (long)blockIdx.z * sB;

  v4f acc[MT][NT] = {};
  const int srow8 = lane >> 3;
  const int cs = (lane & 7) ^ srow8;
  const int lsw = l16 & 7;

  for (int k0 = 0; k0 < K; k0 += 64) {
    __syncthreads();
#pragma unroll
    for (int i = 0; i < TM / 32; ++i) {
      const int is = w + i * 4;
      async16(A + (long)(m0 + is * 8 + srow8) * K + k0 + cs * 8, Ah + is * 512);
    }
#pragma unroll
    for (int i = 0; i < 4; ++i) {
      const int is = w + i * 4;
      async16(B + (long)(n0 + is * 8 + srow8) * K + k0 + cs * 8, Bh + is * 512);
    }
    __syncthreads();

    v8h af[MT][2], bfr[NT][2];
#pragma unroll
    for (int mt = 0; mt < MT; ++mt) {
      const int rr = wm * 64 + mt * 16 + l16;
#pragma unroll
      for (int kk = 0; kk < 2; ++kk) {
        const int c = (kk * 4 + quad) ^ lsw;
        af[mt][kk] = *(v8h*)&Ah[rr * 64 + c * 8];
      }
    }
#pragma unroll
    for (int nt = 0; nt < NT; ++nt) {
      const int rn = wn * WN + nt * 16 + l16;
#pragma unroll
      for (int kk = 0; kk < 2; ++kk) {
        const int c = (kk * 4 + quad) ^ lsw;
        bfr[nt][kk] = *(v8h*)&Bh[rn * 64 + c * 8];
      }
    }
#pragma unroll
    for (int kk = 0; kk < 2; ++kk)
#pragma unroll
      for (int mt = 0; mt < MT; ++mt)
#pragma unroll
        for (int nt = 0; nt < NT; ++nt)
          acc[mt][nt] = __builtin_amdgcn_mfma_f32_16x16x32_f16(
              af[mt][kk], bfr[nt][kk], acc[mt][nt], 0, 0, 0);
  }

  // ---- epilogue (C layout: col = lane&15, row = quad*4 + reg) ----
  const long Cz = (long)blockIdx.z * sC;
  const int region = n0 >> 9;          // block-uniform (OMODE 4)
#pragma unroll
  for (int nt = 0; nt < NT; ++nt) {
    const int gn = n0 + wn * WN + nt * 16 + l16;
    const int gnl = gn & 511;
    const float bv = bias ? bias[gn] : 0.0f;
#pragma unroll
    for (int mt = 0; mt < MT; ++mt) {
      const int gmb = m0 + wm * 64 + mt * 16 + quad * 4;
      if constexpr (OMODE == 4) {
        if (region == 2) {  // vT[z][gnl][m] — 4 consecutive m: one 8B store
          const int z2 = gmb >> 11, ml = gmb & 2047;
          v4h h4;
#pragma unroll
          for (int r = 0; r < 4; ++r)
            h4[r] = (_Float16)(acc[mt][nt][r] * scale + bv);
          *(v4h*)&((_Float16*)Cp3)[((long)z2 * 512 + gnl) * 2048 + ml] = h4;
          continue;
        }
      }
#pragma unroll
      for (int r = 0; r < 4; ++r) {
        const int gm = gmb + r;
        float v = acc[mt][nt][r] * scale + bv;
        if constexpr (ACT == 1)
          v = 0.5f * v * (1.0f + erff(v * 0.7071067811865476f));
        if constexpr (OMODE == 0) {
          ((float*)Cp)[Cz + (long)gm * N + gn] = v;
        } else if constexpr (OMODE == 1) {
          ((_Float16*)Cp)[Cz + (long)gm * N + gn] = (_Float16)v;
        } else {  // OMODE 4, region 0/1
          if (region == 0) {
            ((_Float16*)Cp)[(long)gm * 512 + gnl] = (_Float16)v;
          } else {
            ((_Float16*)Cp2)[(long)gm * 512 + gnl] = (_Float16)v;
          }
        }
      }
    }
  }
}

// ---- row softmax over S=2048 fp16 logits, in place ----
__global__ __launch_bounds__(256) void softmax_k(_Float16* __restrict__ Sc) {
  _Float16* p = Sc + (size_t)blockIdx.x * S;
  const int base = threadIdx.x * 8;
  const v8h a = *(const v8h*)(p + base);
  float v[8];
#pragma unroll
  for (int i = 0; i < 8; ++i) v[i] = (float)a[i];
  float m = -1e30f;
#pragma unroll
  for (int i = 0; i < 8; ++i) m = fmaxf(m, v[i]);
  m = blockMax(m);
  float sum = 0.f;
#pragma unroll
  for (int i = 0; i < 8; ++i) {
    v[i] = exp2f((v[i] - m) * 1.44269504f);
    sum += v[i];
  }
  sum = blockSum(sum);
  const float inv = 1.0f / sum;
  v8h o;
#pragma unroll
  for (int i = 0; i < 8; ++i) o[i] = (_Float16)(v[i] * inv);
  *(v8h*)(p + base) = o;
}

// ---- r = LayerNorm(X + Add) -> X (in place) + fp16 copy rF ----
__global__ __launch_bounds__(256) void ln_res_k(
    float* __restrict__ X, const float* __restrict__ Add,
    const float* __restrict__ g, const float* __restrict__ b,
    _Float16* __restrict__ rF) {
  float* xr = X + (size_t)blockIdx.x * D;
  const float* ar = Add + (size_t)blockIdx.x * D;
  _Float16* rf = rF + (size_t)blockIdx.x * D;
  const int t0 = threadIdx.x, t1 = threadIdx.x + 256;
  const float z0 = xr[t0] + ar[t0];
  const float z1 = xr[t1] + ar[t1];
  const float mu = blockSum(z0 + z1) * (1.0f / D);
  const float d0 = z0 - mu, d1 = z1 - mu;
  const float var = blockSum(d0 * d0 + d1 * d1) * (1.0f / D);
  const float rs = rsqrtf(var + 1e-5f);
  const float v0 = d0 * rs * g[t0] + b[t0];
  const float v1 = d1 * rs * g[t1] + b[t1];
  xr[t0] = v0; xr[t1] = v1;
  rf[t0] = (_Float16)v0; rf[t1] = (_Float16)v1;
}

// ---- out = LayerNorm(R + F), fp32 ----
__global__ __launch_bounds__(256) void ln_out_k(
    const float* __restrict__ R, const float* __restrict__ F,
    const float* __restrict__ g, const float* __restrict__ b,
    float* __restrict__ out) {
  const float* rr = R + (size_t)blockIdx.x * D;
  const float* fr = F + (size_t)blockIdx.x * D;
  float* orow = out + (size_t)blockIdx.x * D;
  const int t0 = threadIdx.x, t1 = threadIdx.x + 256;
  const float z0 = rr[t0] + fr[t0];
  const float z1 = rr[t1] + fr[t1];
  const float mu = blockSum(z0 + z1) * (1.0f / D);
  const float d0 = z0 - mu, d1 = z1 - mu;
  const float var = blockSum(d0 * d0 + d1 * d1) * (1.0f / D);
  const float rs = rsqrtf(var + 1e-5f);
  orow[t0] = d0 * rs * g[t0] + b[t0];
  orow[t1] = d1 * rs * g[t1] + b[t1];
}

extern "C" void kernel_launch(void* const* d_in, const int* in_sizes, int n_in,
                              void* d_out, int out_size, void* d_ws, size_t ws_size,
                              hipStream_t stream) {
  (void)in_sizes; (void)n_in; (void)out_size; (void)ws_size;
  const int*   seq = (const int*)d_in[0];
  const float* emb = (const float*)d_in[1];
  const float* wk  = (const float*)d_in[2];
  const float* bk  = (const float*)d_in[3];
  const float* wq  = (const float*)d_in[4];
  const float* bq  = (const float*)d_in[5];
  const float* wv  = (const float*)d_in[6];
  const float* bv  = (const float*)d_in[7];
  const float* lng = (const float*)d_in[8];
  const float* lnb = (const float*)d_in[9];
  const float* w1  = (const float*)d_in[10];
  const float* b1  = (const float*)d_in[11];
  const float* w2  = (const float*)d_in[12];
  const float* b2  = (const float*)d_in[13];

  // Workspace (MB offsets, lifetimes):
  //  [0,16)    X fp32 (x -> r in-place)
  //  [16,24)   Xh fp16 (dead after QKV)
  //  [24,32)   kF fp16 (dead after scores)  -> rF fp16
  //  [32,40)   qF fp16 (dead after scores)  -> ff fp32 [32,48)
  //  [40,48)   vT fp16 [z][D][S]            (ff tail; vT dead after PV)
  //  [48,80)   Sc fp16, softmax in place (dead after PV) -> hF fp16
  //  [81,97)   attn fp32 (dead after ln_res)
  //  [100,...) wcat 1.5MB, bcat 8KB, w1T 2MB, w2T 2MB
  const size_t MBy = 1024 * 1024;
  char* wsb = (char*)d_ws;
  float*    X    = (float*)wsb;
  _Float16* Xh   = (_Float16*)(wsb + 16 * MBy);
  _Float16* kF   = (_Float16*)(wsb + 24 * MBy);
  _Float16* qF   = (_Float16*)(wsb + 32 * MBy);
  _Float16* vT   = (_Float16*)(wsb + 40 * MBy);
  _Float16* Sc   = (_Float16*)(wsb + 48 * MBy);
  float*    attn = (float*)(wsb + 81 * MBy);
  _Float16* rF   = (_Float16*)(wsb + 24 * MBy);
  _Float16* hF   = (_Float16*)(wsb + 48 * MBy);
  float*    ff   = (float*)(wsb + 32 * MBy);
  _Float16* wcat = (_Float16*)(wsb + 100 * MBy);
  float*    bcat = (float*)(wsb + 102 * MBy);
  _Float16* w1T  = (_Float16*)(wsb + 103 * MBy);
  _Float16* w2T  = (_Float16*)(wsb + 105 * MBy);

  const long SD = (long)S * D, SSl = (long)S * S;

  prep_k<<<11270, 256, 0, stream>>>(wk, wq, wv, w1, w2, bk, bq, bv,
                                    wcat, w1T, w2T, bcat);
  embed_pos_k<<<BS, 256, 0, stream>>>(seq, emb, X, Xh);

  // fused QKV projection: [8192,512] @ wcat^T[512,1536], split epilogue
  mm_k<128, 4, 0><<<dim3(12, 64, 1), 256, 0, stream>>>(
      Xh, wcat, kF, qF, vT, bcat, 1536, D, 0, 0, 0, 1.0f);

  // scores = (k @ q^T)/sqrt(D) -> fp16, batched
  mm_k<128, 1, 0><<<dim3(16, 16, BB), 256, 0, stream>>>(
      kF, qF, Sc, nullptr, nullptr, nullptr, S, D, SD, SD, SSl,
      0.044194173824159216f);

  // softmax in place over Sc
  softmax_k<<<BS, 256, 0, stream>>>(Sc);

  // attn = P @ v (plain GEMM, async staging), batched
  mm_k<64, 0, 0><<<dim3(4, 32, BB), 256, 0, stream>>>(
      Sc, vT, attn, nullptr, nullptr, nullptr, D, S, SSl, (long)D * S, SD,
      1.0f);

  // r = LN(x + attn) -> X (+ fp16 rF)
  ln_res_k<<<BS, 256, 0, stream>>>(X, attn, lng, lnb, rF);

  // h = gelu(r @ w1 + b1) -> fp16
  mm_k<128, 1, 1><<<dim3(16, 64, 1), 256, 0, stream>>>(
      rF, w1T, hF, nullptr, nullptr, b1, DFF, D, 0, 0, 0, 1.0f);
  // ff = h @ w2 + b2 -> fp32
  mm_k<64, 0, 0><<<dim3(4, 128, 1), 256, 0, stream>>>(
      hF, w2T, ff, nullptr, nullptr, b2, D, DFF, 0, 0, 0, 1.0f);

  // out = LN(r + ff)
  ln_out_k<<<BS, 256, 0, stream>>>(X, ff, lng, lnb, (float*)d_out);
}